// Round 23
// baseline (123.824 us; speedup 1.0000x reference)
//
#include <hip/hip_runtime.h>

// MHA forward: B=2, S=2048, D=1024, H=16, dk=64.
// Pipeline: cvt x,W -> bf16; fused QKV GEMM (V transposed out) -> flash attn -> O GEMM.
// R23 (attn): kv-split wave pairing. Block = ONE 128-row q-strip, 8 waves;
// waves w and w+4 own the same 32 q-rows but split each 128-kv tile in half
// (A: kv[0,64), B: kv[64,128)). Fixed-base softmax => O,l are pure kv-sums, so
// partials merge by addition in a one-time LDS epilogue. Every wave active every
// iteration (old strip-pairing idled waves 4-7 for most of big-strip blocks).

#define D_MODEL 1024
#define SEQ     2048
#define NHEAD   16
#define DKH     64
#define MROWS   4096   // B*S

typedef __attribute__((ext_vector_type(8))) short bf16x8;
typedef __attribute__((ext_vector_type(4))) float f32x4;
typedef __attribute__((ext_vector_type(16))) float f32x16;
#define ZERO16 {0.f,0.f,0.f,0.f,0.f,0.f,0.f,0.f,0.f,0.f,0.f,0.f,0.f,0.f,0.f,0.f}

#define GLOBAL_AS(p) ((const __attribute__((address_space(1))) unsigned int*)(p))
#define LDS_AS(p)    ((__attribute__((address_space(3))) unsigned int*)(p))

__device__ __forceinline__ unsigned short f2bf(float f) {
    union { float f; unsigned u; } v; v.f = f;
    unsigned r = (v.u + 0x7fffu + ((v.u >> 16) & 1u)) >> 16;   // RNE
    return (unsigned short)r;
}
__device__ __forceinline__ unsigned pack2_fast(float a, float b) {
    unsigned ua = (__builtin_bit_cast(unsigned, a) + 0x8000u) >> 16;
    unsigned ub = (__builtin_bit_cast(unsigned, b) + 0x8000u) & 0xffff0000u;
    return ua | ub;
}
__device__ __forceinline__ unsigned long long pack4(float4 v) {
    return (unsigned long long)f2bf(v.x)
         | ((unsigned long long)f2bf(v.y) << 16)
         | ((unsigned long long)f2bf(v.z) << 32)
         | ((unsigned long long)f2bf(v.w) << 48);
}
__device__ __forceinline__ unsigned long long pack4f(float a, float b, float c, float d) {
    return (unsigned long long)f2bf(a)
         | ((unsigned long long)f2bf(b) << 16)
         | ((unsigned long long)f2bf(c) << 32)
         | ((unsigned long long)f2bf(d) << 48);
}

// XOR swizzles (involutions, 16B-block-preserving).
__device__ __forceinline__ int swz(int row, int byte)  { return byte ^ ((row & 7) << 4); }   // 128B rows
__device__ __forceinline__ int swzV(int row, int byte) { return byte ^ ((row & 15) << 4); }  // 256B rows

// ---------------------------------------------------------------------------
// fp32 -> bf16 bulk converts
// ---------------------------------------------------------------------------
__global__ __launch_bounds__(256) void cvt_bf16(const float* __restrict__ src,
                                                unsigned short* __restrict__ dst, int n4)
{
    int i = blockIdx.x * 256 + threadIdx.x;
    if (i < n4) {
        float4 v = reinterpret_cast<const float4*>(src)[i];
        reinterpret_cast<unsigned long long*>(dst)[i] = pack4(v);
    }
}
__global__ __launch_bounds__(256) void cvt_w4(const float* s0, const float* s1,
                                              const float* s2, const float* s3,
                                              unsigned short* d0, unsigned short* d1,
                                              unsigned short* d2, unsigned short* d3, int n4)
{
    const float* s = (blockIdx.z == 0) ? s0 : (blockIdx.z == 1) ? s1 : (blockIdx.z == 2) ? s2 : s3;
    unsigned short* d = (blockIdx.z == 0) ? d0 : (blockIdx.z == 1) ? d1 : (blockIdx.z == 2) ? d2 : d3;
    int i = blockIdx.x * 256 + threadIdx.x;
    if (i < n4) {
        float4 v = reinterpret_cast<const float4*>(s)[i];
        reinterpret_cast<unsigned long long*>(d)[i] = pack4(v);
    }
}

// ---------------------------------------------------------------------------
// Shared GEMM body (R20, unchanged): dbuf gload_lds staging, 1 barrier/K-step.
// ---------------------------------------------------------------------------
template<bool W_BF16, bool SWAP>
__device__ __forceinline__ void gemm_body(const unsigned short* __restrict__ Ap,
                                          const void* __restrict__ Wp,
                                          const float* __restrict__ bias,
                                          void* __restrict__ Cp, float oscale,
                                          bool outBF16,
                                          int m0, int n0, unsigned char* lds)
{
    const int tid = threadIdx.x;
    const int w = tid >> 6, l = tid & 63;
    const int wm = (w >> 1) * 64, wn = (w & 1) * 64;
    const int lr = l & 15, lk = l >> 4;

    f32x4 acc[4][4] = {};

    auto stage16 = [&](const unsigned short* base, int ldsOff) {
        #pragma unroll
        for (int i = 0; i < 4; i++) {
            int p = (i * 4 + w) * 1024 + l * 16;
            int row = p >> 7;
            int logical = (p & 127) ^ ((row & 7) << 4);
            const unsigned short* src = base + (size_t)row * D_MODEL + (logical >> 1);
            __builtin_amdgcn_global_load_lds(GLOBAL_AS(src),
                LDS_AS(lds + ldsOff + (i * 4 + w) * 1024), 16, 0, 0);
        }
    };
    auto compute = [&](unsigned char* buf) {
        #pragma unroll
        for (int ks = 0; ks < 2; ks++) {
            bf16x8 af[4], bfr[4];
            #pragma unroll
            for (int rt = 0; rt < 4; rt++) {
                int row = wm + rt * 16 + lr;
                af[rt] = *reinterpret_cast<const bf16x8*>(buf + swz(row, row * 128 + ks * 64 + lk * 16));
            }
            #pragma unroll
            for (int ct = 0; ct < 4; ct++) {
                int row = wn + ct * 16 + lr;
                bfr[ct] = *reinterpret_cast<const bf16x8*>(buf + 16384 + swz(row, row * 128 + ks * 64 + lk * 16));
            }
            #pragma unroll
            for (int rt = 0; rt < 4; rt++)
                #pragma unroll
                for (int ct = 0; ct < 4; ct++) {
                    if constexpr (SWAP)
                        acc[rt][ct] = __builtin_amdgcn_mfma_f32_16x16x32_bf16(bfr[ct], af[rt], acc[rt][ct], 0, 0, 0);
                    else
                        acc[rt][ct] = __builtin_amdgcn_mfma_f32_16x16x32_bf16(af[rt], bfr[ct], acc[rt][ct], 0, 0, 0);
                }
        }
    };

    if constexpr (W_BF16) {
        const unsigned short* W = (const unsigned short*)Wp;
        stage16(Ap + (size_t)m0 * D_MODEL, 0);
        stage16(W + (size_t)n0 * D_MODEL, 16384);
        int cur = 0;
        for (int k0 = 0; k0 < D_MODEL; k0 += 64) {
            __syncthreads();
            if (k0 + 64 < D_MODEL) {
                int nb = (cur ^ 1) * 32768;
                stage16(Ap + (size_t)m0 * D_MODEL + k0 + 64, nb);
                stage16(W + (size_t)n0 * D_MODEL + k0 + 64, nb + 16384);
            }
            compute(lds + cur * 32768);
            cur ^= 1;
        }
    } else {
        float4 rwf[8];
        auto loadWf = [&](int k0) {
            const float* W = (const float*)Wp;
            #pragma unroll
            for (int i = 0; i < 8; i++) {
                int c = tid + i * 256;
                int row = c >> 4, col4 = c & 15;
                rwf[i] = *reinterpret_cast<const float4*>(W + (size_t)(n0 + row) * D_MODEL + k0 + col4 * 4);
            }
        };
        auto storeWf = [&]() {
            #pragma unroll
            for (int i = 0; i < 8; i++) {
                int c = tid + i * 256;
                int row = c >> 4, col4 = c & 15;
                *reinterpret_cast<unsigned long long*>(lds + 16384 + swz(row, row * 128 + col4 * 8)) = pack4(rwf[i]);
            }
        };
        loadWf(0);
        for (int k0 = 0; k0 < D_MODEL; k0 += 64) {
            __syncthreads();
            stage16(Ap + (size_t)m0 * D_MODEL + k0, 0);
            storeWf();
            __syncthreads();
            if (k0 + 64 < D_MODEL) loadWf(k0 + 64);
            compute(lds);
        }
    }

    if constexpr (SWAP) {
        #pragma unroll
        for (int ct = 0; ct < 4; ct++) {
            int nb = n0 + wn + ct * 16 + lk * 4;
            float4 bv = *reinterpret_cast<const float4*>(bias + nb);
            #pragma unroll
            for (int rt = 0; rt < 4; rt++) {
                int m = m0 + wm + rt * 16 + lr;
                float v0 = (acc[rt][ct][0] + bv.x) * oscale;
                float v1 = (acc[rt][ct][1] + bv.y) * oscale;
                float v2 = (acc[rt][ct][2] + bv.z) * oscale;
                float v3 = (acc[rt][ct][3] + bv.w) * oscale;
                if (outBF16)
                    *reinterpret_cast<unsigned long long*>((unsigned short*)Cp + (size_t)m * D_MODEL + nb) =
                        pack4f(v0, v1, v2, v3);
                else {
                    float4 o4 = {v0, v1, v2, v3};
                    *reinterpret_cast<float4*>((float*)Cp + (size_t)m * D_MODEL + nb) = o4;
                }
            }
        }
    } else {
        #pragma unroll
        for (int ct = 0; ct < 4; ct++) {
            int n = n0 + wn + ct * 16 + lr;
            float bv = bias[n];
            #pragma unroll
            for (int rt = 0; rt < 4; rt++) {
                int mb = m0 + wm + rt * 16 + lk * 4;
                *reinterpret_cast<unsigned long long*>((unsigned short*)Cp + (size_t)n * MROWS + mb) =
                    pack4f((acc[rt][ct][0] + bv) * oscale, (acc[rt][ct][1] + bv) * oscale,
                           (acc[rt][ct][2] + bv) * oscale, (acc[rt][ct][3] + bv) * oscale);
            }
        }
    }
}

template<bool W_BF16>
__global__ __launch_bounds__(256) void gemm_qkv(const unsigned short* __restrict__ Xb,
                                                const void* W0, const void* W1, const void* W2,
                                                const float* b0, const float* b1, const float* b2,
                                                void* C0, void* C1, void* C2, float qsc)
{
    __shared__ __align__(16) unsigned char lds[65536];
    int lid = (int)blockIdx.x + 8 * (int)blockIdx.y + 256 * (int)blockIdx.z;  // 768
    int sid = (lid & 7) * 96 + (lid >> 3);                                    // bijective
    int z = sid >> 8, rem = sid & 255;
    int m0 = (rem >> 3) * 128, n0 = (rem & 7) * 128;
    if (z == 2)
        gemm_body<W_BF16, false>(Xb, W2, b2, C2, 1.0f, true, m0, n0, lds);
    else
        gemm_body<W_BF16, true >(Xb, z ? W1 : W0, z ? b1 : b0, z ? C1 : C0,
                                 z ? 1.0f : qsc, true, m0, n0, lds);
}

template<bool W_BF16>
__global__ __launch_bounds__(256) void gemm_o(const unsigned short* __restrict__ Ap,
                                              const void* __restrict__ Wp,
                                              const float* __restrict__ bias,
                                              void* __restrict__ Cp)
{
    __shared__ __align__(16) unsigned char lds[65536];
    int lid = (int)blockIdx.x + 8 * (int)blockIdx.y;   // 256
    int sid = (lid & 7) * 32 + (lid >> 3);
    int m0 = (sid >> 3) * 128, n0 = (sid & 7) * 128;
    gemm_body<W_BF16, true>(Ap, Wp, bias, Cp, 1.0f, false, m0, n0, lds);
}

// ---------------------------------------------------------------------------
// Causal flash attention: swapped-QK 32x32, fixed-base softmax, KVBLK=128 dbuf.
// R23: block = one 128-row strip, 8 waves; waves w/w+4 share 32 q-rows and
// split each tile's kv range (A: [0,64), B: [64,128)). Partial O,l merged by
// addition through LDS at the end. Grid 512 (big strips first, XCD remap).
// ---------------------------------------------------------------------------
__global__ __launch_bounds__(512, 4) void attn_fwd(const unsigned short* __restrict__ Qb,
                                                   const unsigned short* __restrict__ Kb,
                                                   const unsigned short* __restrict__ Vt,
                                                   unsigned short* __restrict__ Ctx)
{
    __shared__ __align__(16) unsigned char klds[2][16384];
    __shared__ __align__(16) unsigned char vlds[2][16384];

    const int tid = threadIdx.x, w = tid >> 6, l = tid & 63;
    const int ql = l & 31, hi = l >> 5;
    int lid = (int)blockIdx.x + 16 * (int)blockIdx.y;    // 0..511
    int sid = (lid & 7) * 64 + (lid >> 3);               // bijective XCD remap
    const int s = 15 - (sid & 15);                       // big strips first
    const int yq = sid >> 4;
    const int b = yq >> 4, h = yq & 15;
    const int q0 = s * 128;
    const int g = w >> 2;                                // kv-half group (0/1)
    const size_t headoff = (size_t)b * SEQ * D_MODEL + (size_t)h * DKH;   // Q/K/Ctx
    const size_t vtoff   = (size_t)h * DKH * MROWS + (size_t)b * SEQ;     // Vt[h*64+d][b*2048+kv]
    const int qrow0 = q0 + (w & 3) * 32;
    const int qg = qrow0 + ql;            // this lane's q row

    // Q B-operand fragments: aq[c] = Q[qg][16c + 8hi .. +8]  (pre-scaled by QSC)
    bf16x8 aq[4];
    #pragma unroll
    for (int c = 0; c < 4; c++)
        aq[c] = *reinterpret_cast<const bf16x8*>(
            Qb + headoff + (size_t)qg * D_MODEL + c * 16 + hi * 8);

    f32x16 o0 = ZERO16, o1 = ZERO16;      // O^T partials (this wave's kv-half)
    float l_s = 0.f;

    // async stage of one 128-kv tile (K 16KB + V^T 16KB) into buffer bi.
    auto stage = [&](int t, int bi) {
        const int kv0 = t * 128;
        #pragma unroll
        for (int i = 0; i < 2; i++) {
            int p = tid * 16 + i * 8192;
            int krow = p >> 7;
            int klb = (p & 127) ^ ((krow & 7) << 4);
            const unsigned short* ksrc = Kb + headoff + (size_t)(kv0 + krow) * D_MODEL + (klb >> 1);
            __builtin_amdgcn_global_load_lds(GLOBAL_AS(ksrc),
                LDS_AS(&klds[bi][0] + i * 8192 + w * 1024), 16, 0, 0);
            int vrow = p >> 8;
            int vlb = (p & 255) ^ ((vrow & 15) << 4);   // 16-way involution
            const unsigned short* vsrc = Vt + vtoff + (size_t)vrow * MROWS + kv0 + (vlb >> 1);
            __builtin_amdgcn_global_load_lds(GLOBAL_AS(vsrc),
                LDS_AS(&vlds[bi][0] + i * 8192 + w * 1024), 16, 0, 0);
        }
    };

    const int ntiles = s + 1;             // covers kv <= q0+127
    stage(0, 0);

    for (int t = 0; t < ntiles; t++) {
        const int kv0 = t * 128;
        const int cur = t & 1;
        __syncthreads();                  // drains stage(t) -> buf[cur] ready;
                                          // all waves done reading buf[cur^1]
        if (t + 1 < ntiles) stage(t + 1, cur ^ 1);   // hidden under compute below

        const int kv0g = kv0 + g * 64;    // this wave's kv-half base
        if (kv0g > qrow0 + 31) continue;  // wave-uniform: half fully masked

        // ---- S^T = K Q^T : this wave's two 32-kv quarters ----
        f32x16 s0 = ZERO16, s1 = ZERO16;
        __builtin_amdgcn_s_setprio(1);
        #pragma unroll
        for (int c = 0; c < 4; c++) {
            const int row0 = g * 64 + ql, row1 = g * 64 + 32 + ql;
            bf16x8 ka0 = *reinterpret_cast<const bf16x8*>(&klds[cur][0] + swz(row0, row0 * 128 + c * 32 + hi * 16));
            bf16x8 ka1 = *reinterpret_cast<const bf16x8*>(&klds[cur][0] + swz(row1, row1 * 128 + c * 32 + hi * 16));
            s0 = __builtin_amdgcn_mfma_f32_32x32x16_bf16(ka0, aq[c], s0, 0, 0, 0);
            s1 = __builtin_amdgcn_mfma_f32_32x32x16_bf16(ka1, aq[c], s1, 0, 0, 0);
        }
        __builtin_amdgcn_s_setprio(0);

        // ---- fixed-base softmax: p = exp2(s); masked -> 0 ----
        float rs = 0.f;
        const bool needmask = (kv0g + 63) > qrow0;   // wave-uniform
        if (needmask) {
            #pragma unroll
            for (int r = 0; r < 16; r++) {
                const int kvc = (r & 3) + 8 * (r >> 2) + 4 * hi;
                int kva = kv0g + kvc;
                float p0 = (kva > qg)      ? 0.f : __builtin_amdgcn_exp2f(s0[r]);
                float p1 = (kva + 32 > qg) ? 0.f : __builtin_amdgcn_exp2f(s1[r]);
                s0[r] = p0; s1[r] = p1;
                rs += p0 + p1;
            }
        } else {
            #pragma unroll
            for (int r = 0; r < 16; r++) {
                float p0 = __builtin_amdgcn_exp2f(s0[r]);
                float p1 = __builtin_amdgcn_exp2f(s1[r]);
                s0[r] = p0; s1[r] = p1;
                rs += p0 + p1;
            }
        }
        rs += __shfl_xor(rs, 32, 64);
        l_s += rs;

        // ---- O^T += V' P over this wave's kv-half (global j = 4g + jl) ----
        #pragma unroll
        for (int jl = 0; jl < 4; jl++) {
            const int j = 4 * g + jl;
            union { bf16x8 v; unsigned u[4]; } pu;
            #pragma unroll
            for (int wd = 0; wd < 4; wd++) {
                const int r0 = 8 * (jl & 1) + 2 * wd;
                float pa0, pa1;
                if (jl < 2) { pa0 = s0[r0]; pa1 = s0[r0 + 1]; }
                else        { pa0 = s1[r0]; pa1 = s1[r0 + 1]; }
                pu.u[wd] = pack2_fast(pa0, pa1);
            }
            union { bf16x8 v; unsigned long long q[2]; } va0, va1;
            const int byte0 = ql * 256 + 32 * j + 8 * hi;
            va0.q[0] = *reinterpret_cast<const unsigned long long*>(&vlds[cur][0] + swzV(ql, byte0));
            va0.q[1] = *reinterpret_cast<const unsigned long long*>(&vlds[cur][0] + swzV(ql, byte0 + 16));
            const int row1 = ql + 32;
            const int byte1 = row1 * 256 + 32 * j + 8 * hi;
            va1.q[0] = *reinterpret_cast<const unsigned long long*>(&vlds[cur][0] + swzV(row1, byte1));
            va1.q[1] = *reinterpret_cast<const unsigned long long*>(&vlds[cur][0] + swzV(row1, byte1 + 16));
            __builtin_amdgcn_s_setprio(1);
            o0 = __builtin_amdgcn_mfma_f32_32x32x16_bf16(va0.v, pu.v, o0, 0, 0, 0);
            o1 = __builtin_amdgcn_mfma_f32_32x32x16_bf16(va1.v, pu.v, o1, 0, 0, 0);
            __builtin_amdgcn_s_setprio(0);
        }
    }

    // ---- merge kv-half partials (group B -> LDS, group A adds) ----
    __syncthreads();                      // all compute done; staging buffers dead
    float* mb = reinterpret_cast<float*>(&klds[0][0]);      // 32KB: 128 rows x 64 d
    float* lb = reinterpret_cast<float*>(&vlds[0][0]);      // 128 floats
    const int rbase = ((w & 3) * 32 + ql) * 64;
    if (w >= 4) {
        #pragma unroll
        for (int g4 = 0; g4 < 4; g4++) {
            const int d0 = 8 * g4 + 4 * hi;
            float4 a = {o0[4 * g4], o0[4 * g4 + 1], o0[4 * g4 + 2], o0[4 * g4 + 3]};
            float4 c = {o1[4 * g4], o1[4 * g4 + 1], o1[4 * g4 + 2], o1[4 * g4 + 3]};
            *reinterpret_cast<float4*>(mb + rbase + d0) = a;
            *reinterpret_cast<float4*>(mb + rbase + 32 + d0) = c;
        }
        if (hi == 0) lb[(w & 3) * 32 + ql] = l_s;
    }
    __syncthreads();
    if (w < 4) {
        float inv = 1.0f / (l_s + lb[(w & 3) * 32 + ql]);
        #pragma unroll
        for (int g4 = 0; g4 < 4; g4++) {
            const int d0 = 8 * g4 + 4 * hi;
            float4 a = *reinterpret_cast<const float4*>(mb + rbase + d0);
            float4 c = *reinterpret_cast<const float4*>(mb + rbase + 32 + d0);
            *reinterpret_cast<unsigned long long*>(Ctx + headoff + (size_t)qg * D_MODEL + d0) =
                pack4f((o0[4 * g4] + a.x) * inv, (o0[4 * g4 + 1] + a.y) * inv,
                       (o0[4 * g4 + 2] + a.z) * inv, (o0[4 * g4 + 3] + a.w) * inv);
            *reinterpret_cast<unsigned long long*>(Ctx + headoff + (size_t)qg * D_MODEL + 32 + d0) =
                pack4f((o1[4 * g4] + c.x) * inv, (o1[4 * g4 + 1] + c.y) * inv,
                       (o1[4 * g4 + 2] + c.z) * inv, (o1[4 * g4 + 3] + c.w) * inv);
        }
    }
}

extern "C" void kernel_launch(void* const* d_in, const int* in_sizes, int n_in,
                              void* d_out, int out_size, void* d_ws, size_t ws_size,
                              hipStream_t stream)
{
    const float* x   = (const float*)d_in[0];
    const float* w_q = (const float*)d_in[2];
    const float* b_q = (const float*)d_in[3];
    const float* w_k = (const float*)d_in[4];
    const float* b_k = (const float*)d_in[5];
    const float* w_v = (const float*)d_in[6];
    const float* b_v = (const float*)d_in[7];
    const float* w_o = (const float*)d_in[8];
    const float* b_o = (const float*)d_in[9];

    const size_t SEG = (size_t)MROWS * D_MODEL;        // 4M elems
    const size_t WSEG = (size_t)D_MODEL * D_MODEL;     // 1M elems
    unsigned short* Qb  = (unsigned short*)d_ws;
    unsigned short* Kb  = Qb + SEG;
    unsigned short* Vt  = Kb + SEG;                    // [1024][4096] (transposed)
    unsigned short* Xb  = Vt + SEG;                    // x bf16; later reused as Ctx
    unsigned short* Ctx = Xb;                          // alias: attn overwrites after x consumed
    unsigned short* Wqb = Xb + SEG;
    unsigned short* Wkb = Wqb + WSEG;
    unsigned short* Wvb = Wkb + WSEG;
    unsigned short* Wob = Wvb + WSEG;
    const bool fullws = ws_size >= (4 * SEG + 4 * WSEG) * 2;   // 40 MB

    const float QSC = 0.125f * 1.44269504088896f;  // 1/sqrt(dk) * log2(e), folded into Q

    dim3 blk(256);
    dim3 qkvgrid(D_MODEL / 128, MROWS / 128, 3);   // (8, 32, 3)
    dim3 ogrid(D_MODEL / 128, MROWS / 128);        // (8, 32)
    dim3 agrid(16, 32);                            // 512 blocks (strips x bh)

    hipLaunchKernelGGL(cvt_bf16, dim3(4096), blk, 0, stream, x, Xb, (int)(SEG / 4));
    if (fullws) {
        hipLaunchKernelGGL(cvt_w4, dim3(1024, 1, 4), blk, 0, stream,
                           w_q, w_k, w_v, w_o, Wqb, Wkb, Wvb, Wob, (int)(WSEG / 4));
        hipLaunchKernelGGL((gemm_qkv<true>), qkvgrid, blk, 0, stream, Xb,
                           (const void*)Wqb, (const void*)Wkb, (const void*)Wvb,
                           b_q, b_k, b_v, (void*)Qb, (void*)Kb, (void*)Vt, QSC);
        hipLaunchKernelGGL(attn_fwd, agrid, dim3(512), 0, stream, Qb, Kb, Vt, Ctx);
        hipLaunchKernelGGL((gemm_o<true>), ogrid, blk, 0, stream, Ctx, (const void*)Wob, b_o, d_out);
    } else {
        hipLaunchKernelGGL((gemm_qkv<false>), qkvgrid, blk, 0, stream, Xb,
                           (const void*)w_q, (const void*)w_k, (const void*)w_v,
                           b_q, b_k, b_v, (void*)Qb, (void*)Kb, (void*)Vt, QSC);
        hipLaunchKernelGGL(attn_fwd, agrid, dim3(512), 0, stream, Qb, Kb, Vt, Ctx);
        hipLaunchKernelGGL((gemm_o<false>), ogrid, blk, 0, stream, Ctx, (const void*)w_o, b_o, d_out);
    }
}

// Round 24
// 97.988 us; speedup vs baseline: 1.2637x; 1.2637x over previous
//
#include <hip/hip_runtime.h>

// MHA forward: B=2, S=2048, D=1024, H=16, dk=64.  (R24 = verbatim revert to R22,
// the empirical best: 99.0-99.5 us total.)
// Pipeline: cvt x,W -> bf16; fused QKV GEMM (V transposed out) -> flash attn -> O GEMM.
// attn: swapped-QK 32x32, strip-paired blocks, fixed-base softmax, KVBLK=128 dbuf,
// 16-way V swizzle, split PV accumulators.

#define D_MODEL 1024
#define SEQ     2048
#define NHEAD   16
#define DKH     64
#define MROWS   4096   // B*S

typedef __attribute__((ext_vector_type(8))) short bf16x8;
typedef __attribute__((ext_vector_type(4))) float f32x4;
typedef __attribute__((ext_vector_type(16))) float f32x16;
#define ZERO16 {0.f,0.f,0.f,0.f,0.f,0.f,0.f,0.f,0.f,0.f,0.f,0.f,0.f,0.f,0.f,0.f}

#define GLOBAL_AS(p) ((const __attribute__((address_space(1))) unsigned int*)(p))
#define LDS_AS(p)    ((__attribute__((address_space(3))) unsigned int*)(p))

__device__ __forceinline__ unsigned short f2bf(float f) {
    union { float f; unsigned u; } v; v.f = f;
    unsigned r = (v.u + 0x7fffu + ((v.u >> 16) & 1u)) >> 16;   // RNE
    return (unsigned short)r;
}
__device__ __forceinline__ unsigned pack2_fast(float a, float b) {
    unsigned ua = (__builtin_bit_cast(unsigned, a) + 0x8000u) >> 16;
    unsigned ub = (__builtin_bit_cast(unsigned, b) + 0x8000u) & 0xffff0000u;
    return ua | ub;
}
__device__ __forceinline__ unsigned long long pack4(float4 v) {
    return (unsigned long long)f2bf(v.x)
         | ((unsigned long long)f2bf(v.y) << 16)
         | ((unsigned long long)f2bf(v.z) << 32)
         | ((unsigned long long)f2bf(v.w) << 48);
}
__device__ __forceinline__ unsigned long long pack4f(float a, float b, float c, float d) {
    return (unsigned long long)f2bf(a)
         | ((unsigned long long)f2bf(b) << 16)
         | ((unsigned long long)f2bf(c) << 32)
         | ((unsigned long long)f2bf(d) << 48);
}

// XOR swizzles (involutions, 16B-block-preserving).
__device__ __forceinline__ int swz(int row, int byte)  { return byte ^ ((row & 7) << 4); }   // 128B rows
__device__ __forceinline__ int swzV(int row, int byte) { return byte ^ ((row & 15) << 4); }  // 256B rows

// ---------------------------------------------------------------------------
// fp32 -> bf16 bulk converts
// ---------------------------------------------------------------------------
__global__ __launch_bounds__(256) void cvt_bf16(const float* __restrict__ src,
                                                unsigned short* __restrict__ dst, int n4)
{
    int i = blockIdx.x * 256 + threadIdx.x;
    if (i < n4) {
        float4 v = reinterpret_cast<const float4*>(src)[i];
        reinterpret_cast<unsigned long long*>(dst)[i] = pack4(v);
    }
}
__global__ __launch_bounds__(256) void cvt_w4(const float* s0, const float* s1,
                                              const float* s2, const float* s3,
                                              unsigned short* d0, unsigned short* d1,
                                              unsigned short* d2, unsigned short* d3, int n4)
{
    const float* s = (blockIdx.z == 0) ? s0 : (blockIdx.z == 1) ? s1 : (blockIdx.z == 2) ? s2 : s3;
    unsigned short* d = (blockIdx.z == 0) ? d0 : (blockIdx.z == 1) ? d1 : (blockIdx.z == 2) ? d2 : d3;
    int i = blockIdx.x * 256 + threadIdx.x;
    if (i < n4) {
        float4 v = reinterpret_cast<const float4*>(s)[i];
        reinterpret_cast<unsigned long long*>(d)[i] = pack4(v);
    }
}

// ---------------------------------------------------------------------------
// Shared GEMM body (R20): dbuf gload_lds staging, 1 barrier/K-step.
// ---------------------------------------------------------------------------
template<bool W_BF16, bool SWAP>
__device__ __forceinline__ void gemm_body(const unsigned short* __restrict__ Ap,
                                          const void* __restrict__ Wp,
                                          const float* __restrict__ bias,
                                          void* __restrict__ Cp, float oscale,
                                          bool outBF16,
                                          int m0, int n0, unsigned char* lds)
{
    const int tid = threadIdx.x;
    const int w = tid >> 6, l = tid & 63;
    const int wm = (w >> 1) * 64, wn = (w & 1) * 64;
    const int lr = l & 15, lk = l >> 4;

    f32x4 acc[4][4] = {};

    auto stage16 = [&](const unsigned short* base, int ldsOff) {
        #pragma unroll
        for (int i = 0; i < 4; i++) {
            int p = (i * 4 + w) * 1024 + l * 16;
            int row = p >> 7;
            int logical = (p & 127) ^ ((row & 7) << 4);
            const unsigned short* src = base + (size_t)row * D_MODEL + (logical >> 1);
            __builtin_amdgcn_global_load_lds(GLOBAL_AS(src),
                LDS_AS(lds + ldsOff + (i * 4 + w) * 1024), 16, 0, 0);
        }
    };
    auto compute = [&](unsigned char* buf) {
        #pragma unroll
        for (int ks = 0; ks < 2; ks++) {
            bf16x8 af[4], bfr[4];
            #pragma unroll
            for (int rt = 0; rt < 4; rt++) {
                int row = wm + rt * 16 + lr;
                af[rt] = *reinterpret_cast<const bf16x8*>(buf + swz(row, row * 128 + ks * 64 + lk * 16));
            }
            #pragma unroll
            for (int ct = 0; ct < 4; ct++) {
                int row = wn + ct * 16 + lr;
                bfr[ct] = *reinterpret_cast<const bf16x8*>(buf + 16384 + swz(row, row * 128 + ks * 64 + lk * 16));
            }
            #pragma unroll
            for (int rt = 0; rt < 4; rt++)
                #pragma unroll
                for (int ct = 0; ct < 4; ct++) {
                    if constexpr (SWAP)
                        acc[rt][ct] = __builtin_amdgcn_mfma_f32_16x16x32_bf16(bfr[ct], af[rt], acc[rt][ct], 0, 0, 0);
                    else
                        acc[rt][ct] = __builtin_amdgcn_mfma_f32_16x16x32_bf16(af[rt], bfr[ct], acc[rt][ct], 0, 0, 0);
                }
        }
    };

    if constexpr (W_BF16) {
        const unsigned short* W = (const unsigned short*)Wp;
        stage16(Ap + (size_t)m0 * D_MODEL, 0);
        stage16(W + (size_t)n0 * D_MODEL, 16384);
        int cur = 0;
        for (int k0 = 0; k0 < D_MODEL; k0 += 64) {
            __syncthreads();
            if (k0 + 64 < D_MODEL) {
                int nb = (cur ^ 1) * 32768;
                stage16(Ap + (size_t)m0 * D_MODEL + k0 + 64, nb);
                stage16(W + (size_t)n0 * D_MODEL + k0 + 64, nb + 16384);
            }
            compute(lds + cur * 32768);
            cur ^= 1;
        }
    } else {
        float4 rwf[8];
        auto loadWf = [&](int k0) {
            const float* W = (const float*)Wp;
            #pragma unroll
            for (int i = 0; i < 8; i++) {
                int c = tid + i * 256;
                int row = c >> 4, col4 = c & 15;
                rwf[i] = *reinterpret_cast<const float4*>(W + (size_t)(n0 + row) * D_MODEL + k0 + col4 * 4);
            }
        };
        auto storeWf = [&]() {
            #pragma unroll
            for (int i = 0; i < 8; i++) {
                int c = tid + i * 256;
                int row = c >> 4, col4 = c & 15;
                *reinterpret_cast<unsigned long long*>(lds + 16384 + swz(row, row * 128 + col4 * 8)) = pack4(rwf[i]);
            }
        };
        loadWf(0);
        for (int k0 = 0; k0 < D_MODEL; k0 += 64) {
            __syncthreads();
            stage16(Ap + (size_t)m0 * D_MODEL + k0, 0);
            storeWf();
            __syncthreads();
            if (k0 + 64 < D_MODEL) loadWf(k0 + 64);
            compute(lds);
        }
    }

    if constexpr (SWAP) {
        #pragma unroll
        for (int ct = 0; ct < 4; ct++) {
            int nb = n0 + wn + ct * 16 + lk * 4;
            float4 bv = *reinterpret_cast<const float4*>(bias + nb);
            #pragma unroll
            for (int rt = 0; rt < 4; rt++) {
                int m = m0 + wm + rt * 16 + lr;
                float v0 = (acc[rt][ct][0] + bv.x) * oscale;
                float v1 = (acc[rt][ct][1] + bv.y) * oscale;
                float v2 = (acc[rt][ct][2] + bv.z) * oscale;
                float v3 = (acc[rt][ct][3] + bv.w) * oscale;
                if (outBF16)
                    *reinterpret_cast<unsigned long long*>((unsigned short*)Cp + (size_t)m * D_MODEL + nb) =
                        pack4f(v0, v1, v2, v3);
                else {
                    float4 o4 = {v0, v1, v2, v3};
                    *reinterpret_cast<float4*>((float*)Cp + (size_t)m * D_MODEL + nb) = o4;
                }
            }
        }
    } else {
        #pragma unroll
        for (int ct = 0; ct < 4; ct++) {
            int n = n0 + wn + ct * 16 + lr;
            float bv = bias[n];
            #pragma unroll
            for (int rt = 0; rt < 4; rt++) {
                int mb = m0 + wm + rt * 16 + lk * 4;
                *reinterpret_cast<unsigned long long*>((unsigned short*)Cp + (size_t)n * MROWS + mb) =
                    pack4f((acc[rt][ct][0] + bv) * oscale, (acc[rt][ct][1] + bv) * oscale,
                           (acc[rt][ct][2] + bv) * oscale, (acc[rt][ct][3] + bv) * oscale);
            }
        }
    }
}

template<bool W_BF16>
__global__ __launch_bounds__(256) void gemm_qkv(const unsigned short* __restrict__ Xb,
                                                const void* W0, const void* W1, const void* W2,
                                                const float* b0, const float* b1, const float* b2,
                                                void* C0, void* C1, void* C2, float qsc)
{
    __shared__ __align__(16) unsigned char lds[65536];
    int lid = (int)blockIdx.x + 8 * (int)blockIdx.y + 256 * (int)blockIdx.z;  // 768
    int sid = (lid & 7) * 96 + (lid >> 3);                                    // bijective
    int z = sid >> 8, rem = sid & 255;
    int m0 = (rem >> 3) * 128, n0 = (rem & 7) * 128;
    if (z == 2)
        gemm_body<W_BF16, false>(Xb, W2, b2, C2, 1.0f, true, m0, n0, lds);
    else
        gemm_body<W_BF16, true >(Xb, z ? W1 : W0, z ? b1 : b0, z ? C1 : C0,
                                 z ? 1.0f : qsc, true, m0, n0, lds);
}

template<bool W_BF16>
__global__ __launch_bounds__(256) void gemm_o(const unsigned short* __restrict__ Ap,
                                              const void* __restrict__ Wp,
                                              const float* __restrict__ bias,
                                              void* __restrict__ Cp)
{
    __shared__ __align__(16) unsigned char lds[65536];
    int lid = (int)blockIdx.x + 8 * (int)blockIdx.y;   // 256
    int sid = (lid & 7) * 32 + (lid >> 3);
    int m0 = (sid >> 3) * 128, n0 = (sid & 7) * 128;
    gemm_body<W_BF16, true>(Ap, Wp, bias, Cp, 1.0f, false, m0, n0, lds);
}

// ---------------------------------------------------------------------------
// Causal flash attention, swapped-QK 32x32, strip-paired blocks, fixed-base
// softmax, KVBLK=128 dbuf, 16-way V swizzle, split PV accumulators.
// ---------------------------------------------------------------------------
__global__ __launch_bounds__(512, 2) void attn_fwd(const unsigned short* __restrict__ Qb,
                                                   const unsigned short* __restrict__ Kb,
                                                   const unsigned short* __restrict__ Vt,
                                                   unsigned short* __restrict__ Ctx)
{
    __shared__ __align__(16) unsigned char klds[2][16384];
    __shared__ __align__(16) unsigned char vlds[2][16384];

    const int tid = threadIdx.x, w = tid >> 6, l = tid & 63;
    const int ql = l & 31, hi = l >> 5;
    int lid = (int)blockIdx.x + 8 * (int)blockIdx.y;     // 0..255
    int sid = (lid & 7) * 32 + (lid >> 3);               // XCD remap: 4 bh per XCD
    const int bh = sid >> 3, pr = sid & 7;
    const int b = bh >> 4, h = bh & 15;
    const int q0A = (15 - pr) * 128;                     // big strip (waves 0-3)
    const int q0w = (w < 4) ? q0A : pr * 128;            // this wave's strip
    const size_t headoff = (size_t)b * SEQ * D_MODEL + (size_t)h * DKH;   // Q/K/Ctx
    const size_t vtoff   = (size_t)h * DKH * MROWS + (size_t)b * SEQ;     // Vt[h*64+d][b*2048+kv]
    const int qrow0 = q0w + (w & 3) * 32;
    const int qg = qrow0 + ql;            // this lane's q row

    // Q B-operand fragments: aq[c] = Q[qg][16c + 8hi .. +8]  (pre-scaled by QSC)
    bf16x8 aq[4];
    #pragma unroll
    for (int c = 0; c < 4; c++)
        aq[c] = *reinterpret_cast<const bf16x8*>(
            Qb + headoff + (size_t)qg * D_MODEL + c * 16 + hi * 8);

    f32x16 o0A = ZERO16, o0B = ZERO16, o1A = ZERO16, o1B = ZERO16;
    float l_s = 0.f;

    // async stage of one 128-kv tile (K 16KB + V^T 16KB) into buffer bi.
    auto stage = [&](int t, int bi) {
        const int kv0 = t * 128;
        #pragma unroll
        for (int i = 0; i < 2; i++) {
            int p = tid * 16 + i * 8192;
            int krow = p >> 7;
            int klb = (p & 127) ^ ((krow & 7) << 4);
            const unsigned short* ksrc = Kb + headoff + (size_t)(kv0 + krow) * D_MODEL + (klb >> 1);
            __builtin_amdgcn_global_load_lds(GLOBAL_AS(ksrc),
                LDS_AS(&klds[bi][0] + i * 8192 + w * 1024), 16, 0, 0);
            int vrow = p >> 8;
            int vlb = (p & 255) ^ ((vrow & 15) << 4);   // 16-way involution
            const unsigned short* vsrc = Vt + vtoff + (size_t)vrow * MROWS + kv0 + (vlb >> 1);
            __builtin_amdgcn_global_load_lds(GLOBAL_AS(vsrc),
                LDS_AS(&vlds[bi][0] + i * 8192 + w * 1024), 16, 0, 0);
        }
    };

    const int ntiles = 16 - pr;           // covers kv <= q0A+127
    stage(0, 0);

    for (int t = 0; t < ntiles; t++) {
        const int kv0 = t * 128;
        const int cur = t & 1;
        __syncthreads();                  // drains stage(t) -> buf[cur] ready;
                                          // all waves done reading buf[cur^1]
        if (t + 1 < ntiles) stage(t + 1, cur ^ 1);   // hidden under compute below

        if (kv0 > qrow0 + 31) continue;   // wave-uniform: tile fully masked for this wave

        // ---- S^T = K Q^T : four 32-kv quarters, K=64 via 4 chained mfmas ----
        f32x16 s0 = ZERO16, s1 = ZERO16, s2 = ZERO16, s3 = ZERO16;
        __builtin_amdgcn_s_setprio(1);
        #pragma unroll
        for (int c = 0; c < 4; c++) {
            bf16x8 ka0 = *reinterpret_cast<const bf16x8*>(&klds[cur][0] + swz(ql,      ql * 128        + c * 32 + hi * 16));
            bf16x8 ka1 = *reinterpret_cast<const bf16x8*>(&klds[cur][0] + swz(ql + 32, (ql + 32) * 128 + c * 32 + hi * 16));
            bf16x8 ka2 = *reinterpret_cast<const bf16x8*>(&klds[cur][0] + swz(ql + 64, (ql + 64) * 128 + c * 32 + hi * 16));
            bf16x8 ka3 = *reinterpret_cast<const bf16x8*>(&klds[cur][0] + swz(ql + 96, (ql + 96) * 128 + c * 32 + hi * 16));
            s0 = __builtin_amdgcn_mfma_f32_32x32x16_bf16(ka0, aq[c], s0, 0, 0, 0);
            s1 = __builtin_amdgcn_mfma_f32_32x32x16_bf16(ka1, aq[c], s1, 0, 0, 0);
            s2 = __builtin_amdgcn_mfma_f32_32x32x16_bf16(ka2, aq[c], s2, 0, 0, 0);
            s3 = __builtin_amdgcn_mfma_f32_32x32x16_bf16(ka3, aq[c], s3, 0, 0, 0);
        }
        __builtin_amdgcn_s_setprio(0);

        // ---- fixed-base softmax: p = exp2(s); masked -> 0 ----
        float rs = 0.f;
        const bool needmask = (kv0 + 127) > qrow0;   // wave-uniform
        if (needmask) {
            #pragma unroll
            for (int r = 0; r < 16; r++) {
                const int kvc = (r & 3) + 8 * (r >> 2) + 4 * hi;
                int kva = kv0 + kvc;
                float p0 = (kva > qg)      ? 0.f : __builtin_amdgcn_exp2f(s0[r]);
                float p1 = (kva + 32 > qg) ? 0.f : __builtin_amdgcn_exp2f(s1[r]);
                float p2 = (kva + 64 > qg) ? 0.f : __builtin_amdgcn_exp2f(s2[r]);
                float p3 = (kva + 96 > qg) ? 0.f : __builtin_amdgcn_exp2f(s3[r]);
                s0[r] = p0; s1[r] = p1; s2[r] = p2; s3[r] = p3;
                rs += (p0 + p1) + (p2 + p3);
            }
        } else {
            #pragma unroll
            for (int r = 0; r < 16; r++) {
                float p0 = __builtin_amdgcn_exp2f(s0[r]);
                float p1 = __builtin_amdgcn_exp2f(s1[r]);
                float p2 = __builtin_amdgcn_exp2f(s2[r]);
                float p3 = __builtin_amdgcn_exp2f(s3[r]);
                s0[r] = p0; s1[r] = p1; s2[r] = p2; s3[r] = p3;
                rs += (p0 + p1) + (p2 + p3);
            }
        }
        rs += __shfl_xor(rs, 32, 64);
        l_s += rs;

        // ---- O^T += V' P : split accumulators (j-parity) halve chain depth ----
        #pragma unroll
        for (int j = 0; j < 8; j++) {
            union { bf16x8 v; unsigned u[4]; } pu;
            #pragma unroll
            for (int wd = 0; wd < 4; wd++) {
                const int r0 = 8 * (j & 1) + 2 * wd;
                float pa0, pa1;
                if (j < 2)      { pa0 = s0[r0]; pa1 = s0[r0 + 1]; }
                else if (j < 4) { pa0 = s1[r0]; pa1 = s1[r0 + 1]; }
                else if (j < 6) { pa0 = s2[r0]; pa1 = s2[r0 + 1]; }
                else            { pa0 = s3[r0]; pa1 = s3[r0 + 1]; }
                pu.u[wd] = pack2_fast(pa0, pa1);
            }
            union { bf16x8 v; unsigned long long q[2]; } va0, va1;
            const int byte0 = ql * 256 + 32 * j + 8 * hi;
            va0.q[0] = *reinterpret_cast<const unsigned long long*>(&vlds[cur][0] + swzV(ql, byte0));
            va0.q[1] = *reinterpret_cast<const unsigned long long*>(&vlds[cur][0] + swzV(ql, byte0 + 16));
            const int row1 = ql + 32;
            const int byte1 = row1 * 256 + 32 * j + 8 * hi;
            va1.q[0] = *reinterpret_cast<const unsigned long long*>(&vlds[cur][0] + swzV(row1, byte1));
            va1.q[1] = *reinterpret_cast<const unsigned long long*>(&vlds[cur][0] + swzV(row1, byte1 + 16));
            __builtin_amdgcn_s_setprio(1);
            if (j & 1) {
                o0B = __builtin_amdgcn_mfma_f32_32x32x16_bf16(va0.v, pu.v, o0B, 0, 0, 0);
                o1B = __builtin_amdgcn_mfma_f32_32x32x16_bf16(va1.v, pu.v, o1B, 0, 0, 0);
            } else {
                o0A = __builtin_amdgcn_mfma_f32_32x32x16_bf16(va0.v, pu.v, o0A, 0, 0, 0);
                o1A = __builtin_amdgcn_mfma_f32_32x32x16_bf16(va1.v, pu.v, o1A, 0, 0, 0);
            }
            __builtin_amdgcn_s_setprio(0);
        }
    }

    // ---- epilogue: merge accumulator pairs, normalize, store ctx ----
    float inv = 1.0f / l_s;
    #pragma unroll
    for (int g = 0; g < 4; g++) {
        const int d0 = 8 * g + 4 * hi;
        *reinterpret_cast<unsigned long long*>(Ctx + headoff + (size_t)qg * D_MODEL + d0) =
            pack4f((o0A[4 * g] + o0B[4 * g]) * inv, (o0A[4 * g + 1] + o0B[4 * g + 1]) * inv,
                   (o0A[4 * g + 2] + o0B[4 * g + 2]) * inv, (o0A[4 * g + 3] + o0B[4 * g + 3]) * inv);
        *reinterpret_cast<unsigned long long*>(Ctx + headoff + (size_t)qg * D_MODEL + 32 + d0) =
            pack4f((o1A[4 * g] + o1B[4 * g]) * inv, (o1A[4 * g + 1] + o1B[4 * g + 1]) * inv,
                   (o1A[4 * g + 2] + o1B[4 * g + 2]) * inv, (o1A[4 * g + 3] + o1B[4 * g + 3]) * inv);
    }
}

extern "C" void kernel_launch(void* const* d_in, const int* in_sizes, int n_in,
                              void* d_out, int out_size, void* d_ws, size_t ws_size,
                              hipStream_t stream)
{
    const float* x   = (const float*)d_in[0];
    const float* w_q = (const float*)d_in[2];
    const float* b_q = (const float*)d_in[3];
    const float* w_k = (const float*)d_in[4];
    const float* b_k = (const float*)d_in[5];
    const float* w_v = (const float*)d_in[6];
    const float* b_v = (const float*)d_in[7];
    const float* w_o = (const float*)d_in[8];
    const float* b_o = (const float*)d_in[9];

    const size_t SEG = (size_t)MROWS * D_MODEL;        // 4M elems
    const size_t WSEG = (size_t)D_MODEL * D_MODEL;     // 1M elems
    unsigned short* Qb  = (unsigned short*)d_ws;
    unsigned short* Kb  = Qb + SEG;
    unsigned short* Vt  = Kb + SEG;                    // [1024][4096] (transposed)
    unsigned short* Xb  = Vt + SEG;                    // x bf16; later reused as Ctx
    unsigned short* Ctx = Xb;                          // alias: attn overwrites after x consumed
    unsigned short* Wqb = Xb + SEG;
    unsigned short* Wkb = Wqb + WSEG;
    unsigned short* Wvb = Wkb + WSEG;
    unsigned short* Wob = Wvb + WSEG;
    const bool fullws = ws_size >= (4 * SEG + 4 * WSEG) * 2;   // 40 MB

    const float QSC = 0.125f * 1.44269504088896f;  // 1/sqrt(dk) * log2(e), folded into Q

    dim3 blk(256);
    dim3 qkvgrid(D_MODEL / 128, MROWS / 128, 3);   // (8, 32, 3)
    dim3 ogrid(D_MODEL / 128, MROWS / 128);        // (8, 32)
    dim3 agrid(8, 32);                             // 256 blocks (pairs x bh)

    hipLaunchKernelGGL(cvt_bf16, dim3(4096), blk, 0, stream, x, Xb, (int)(SEG / 4));
    if (fullws) {
        hipLaunchKernelGGL(cvt_w4, dim3(1024, 1, 4), blk, 0, stream,
                           w_q, w_k, w_v, w_o, Wqb, Wkb, Wvb, Wob, (int)(WSEG / 4));
        hipLaunchKernelGGL((gemm_qkv<true>), qkvgrid, blk, 0, stream, Xb,
                           (const void*)Wqb, (const void*)Wkb, (const void*)Wvb,
                           b_q, b_k, b_v, (void*)Qb, (void*)Kb, (void*)Vt, QSC);
        hipLaunchKernelGGL(attn_fwd, agrid, dim3(512), 0, stream, Qb, Kb, Vt, Ctx);
        hipLaunchKernelGGL((gemm_o<true>), ogrid, blk, 0, stream, Ctx, (const void*)Wob, b_o, d_out);
    } else {
        hipLaunchKernelGGL((gemm_qkv<false>), qkvgrid, blk, 0, stream, Xb,
                           (const void*)w_q, (const void*)w_k, (const void*)w_v,
                           b_q, b_k, b_v, (void*)Qb, (void*)Kb, (void*)Vt, QSC);
        hipLaunchKernelGGL(attn_fwd, agrid, dim3(512), 0, stream, Qb, Kb, Vt, Ctx);
        hipLaunchKernelGGL((gemm_o<false>), ogrid, blk, 0, stream, Ctx, (const void*)w_o, b_o, d_out);
    }
}